// Round 9
// baseline (124.724 us; speedup 1.0000x reference)
//
#include <hip/hip_runtime.h>
#include <math.h>

#define BATCH 32
#define LSEQ  2048
#define DIM   1024
#define DIM2  2048

constexpr float EPSF = 1e-5f;

constexpr int CHUNKS = 64;                    // max k1 chunks per batch (32 rows each)

constexpr int KSEG1 = 32;
constexpr int NSEG1 = DIM / KSEG1;            // 32 k-segments for matmul 1
constexpr int KSEG2 = 32;
constexpr int NSEG2 = DIM2 / KSEG2;           // 64 k-segments for matmul 2

constexpr int K4_BLKS = 8;                    // k4 blocks per batch

typedef float f4v __attribute__((ext_vector_type(4)));

// ---------------------------------------------------------------------------
// K1: fused {mask compaction + gather-sum} — no separate k0, no rowlist.
// Every block re-runs the deterministic per-batch compaction (8 mask loads +
// block prefix scan; mask L2-resident after first touch), then gathers only
// context rows (~50% of x skipped). chunk-0 block publishes cnt/ntgt.
// dtype sniff: mask storage may be int32 or int64; any nonzero at an odd
// int32 word => int32 (int64 high words all zero; P[false int64] = 2^-256).
// ---------------------------------------------------------------------------
__global__ __launch_bounds__(256) void k1_fused(const float* __restrict__ x,
                                                const int* __restrict__ m32,
                                                float* __restrict__ psum,
                                                int* __restrict__ cnt,
                                                int* __restrict__ ntgt) {
    const int chunk = blockIdx.x;
    const int b     = blockIdx.y;
    const int t     = threadIdx.x;
    const int wave  = t >> 6, lane = t & 63;

    __shared__ unsigned long long pbw[4];
    __shared__ int wsum[4];
    __shared__ int sidx[32];

    // ---- dtype sniff ----
    const int probe = m32[(size_t)b * 2048 + 8 * t + 1];
    const unsigned long long pb = __ballot(probe != 0);
    if (lane == 0) pbw[wave] = pb;
    __syncthreads();
    const int stride = ((pbw[0] | pbw[1] | pbw[2] | pbw[3]) != 0ull) ? 1 : 2;

    // ---- context flags for my 8 rows + block prefix scan ----
    const int base = t * 8;
    int f[8];
    int ls = 0;
    #pragma unroll
    for (int k = 0; k < 8; ++k) {
        f[k] = (m32[((size_t)b * 2048 + base + k) * (size_t)stride] == 0) ? 1 : 0;
        ls += f[k];
    }
    int v = ls;
    #pragma unroll
    for (int o = 1; o < 64; o <<= 1) {
        const int u = __shfl_up(v, o, 64);
        if (lane >= o) v += u;
    }
    if (lane == 63) wsum[wave] = v;
    __syncthreads();
    int wbase = 0;
    for (int w = 0; w < wave; ++w) wbase += wsum[w];
    const int excl  = wbase + v - ls;          // exclusive offset of my first ctx row
    const int total = wsum[0] + wsum[1] + wsum[2] + wsum[3];

    if (chunk == 0 && t == 0) { cnt[b] = total; ntgt[b] = LSEQ - total; }

    const int nch = (total + 31) >> 5;
    if (chunk >= nch) return;                  // block-uniform
    const int rbeg = chunk * 32;
    const int rcnt = min(32, total - rbeg);

    // ---- deposit my rows that land in this chunk's window ----
    int c = 0;
    #pragma unroll
    for (int k = 0; k < 8; ++k) {
        if (f[k]) {
            const int pos = excl + c;
            if (pos >= rbeg && pos < rbeg + 32) sidx[pos - rbeg] = base + k;
            ++c;
        }
    }
    __syncthreads();

    // ---- gather-sum ----
    const float* xb = x + (size_t)b * LSEQ * DIM + t * 4;
    float4 acc = make_float4(0.f, 0.f, 0.f, 0.f);
    if (rcnt == 32) {                          // fast path: unconditional
        #pragma unroll 8
        for (int r = 0; r < 32; ++r) {
            const float4 vv = *(const float4*)(xb + (size_t)sidx[r] * DIM);
            acc.x += vv.x; acc.y += vv.y; acc.z += vv.z; acc.w += vv.w;
        }
    } else {
        for (int r = 0; r < rcnt; ++r) {
            const float4 vv = *(const float4*)(xb + (size_t)sidx[r] * DIM);
            acc.x += vv.x; acc.y += vv.y; acc.z += vv.z; acc.w += vv.w;
        }
    }
    *(float4*)(psum + ((size_t)b * CHUNKS + chunk) * DIM + t * 4) = acc;
}

// ---------------------------------------------------------------------------
// K3a (fused k2): stage mean directly from psum chunks (divide by cnt), then
// p1[ks][b][j] = mean[b, k-seg] @ W1[k-seg, j]. W1 read exactly once total.
// ---------------------------------------------------------------------------
__global__ __launch_bounds__(256) void k3a_h(const float* __restrict__ psum,
                                             const int* __restrict__ cnt,
                                             const float* __restrict__ W1,
                                             float* __restrict__ p1) {
    const int j  = blockIdx.x * 256 + threadIdx.x;  // 0..2047
    const int ks = blockIdx.y;
    const int k0 = ks * KSEG1;

    __shared__ float mlds[BATCH][KSEG1];            // 4 KB
    {
        // 256 threads x one float4 = 1024 staged values
        const int b  = threadIdx.x >> 3;            // 0..31
        const int kq = threadIdx.x & 7;             // 0..7 -> cols kq*4..+4
        const int cb = cnt[b];
        const int nch = (cb + 31) >> 5;
        float4 s = make_float4(0.f, 0.f, 0.f, 0.f);
        for (int c = 0; c < nch; ++c) {
            const float4 vv = *(const float4*)(psum + ((size_t)b * CHUNKS + c) * DIM + k0 + kq * 4);
            s.x += vv.x; s.y += vv.y; s.z += vv.z; s.w += vv.w;
        }
        const float inv = 1.f / (float)(cb > 1 ? cb : 1);
        *(float4*)&mlds[b][kq * 4] = make_float4(s.x * inv, s.y * inv, s.z * inv, s.w * inv);
    }
    __syncthreads();

    float acc[BATCH];
    #pragma unroll
    for (int b = 0; b < BATCH; ++b) acc[b] = 0.f;

    #pragma unroll
    for (int k4 = 0; k4 < KSEG1 / 4; ++k4) {
        const float w0 = W1[(size_t)(k0 + 4 * k4 + 0) * DIM2 + j];
        const float w1 = W1[(size_t)(k0 + 4 * k4 + 1) * DIM2 + j];
        const float w2 = W1[(size_t)(k0 + 4 * k4 + 2) * DIM2 + j];
        const float w3 = W1[(size_t)(k0 + 4 * k4 + 3) * DIM2 + j];
        #pragma unroll
        for (int b = 0; b < BATCH; ++b) {
            const float4 m4 = *(const float4*)&mlds[b][k4 * 4];
            acc[b] += m4.x * w0; acc[b] += m4.y * w1;
            acc[b] += m4.z * w2; acc[b] += m4.w * w3;
        }
    }
    #pragma unroll
    for (int b = 0; b < BATCH; ++b)
        p1[((size_t)ks * BATCH + b) * DIM2 + j] = acc[b];
}

__device__ __forceinline__ float wave_sum(float v) {
    #pragma unroll
    for (int o = 32; o > 0; o >>= 1) v += __shfl_down(v, o, 64);
    return v;
}

// ---------------------------------------------------------------------------
// K3b: h = sum(p1) + b1; gelu(erf); LayerNorm -> hn. One block per batch row.
// ---------------------------------------------------------------------------
__global__ __launch_bounds__(256) void k3b_ln(const float* __restrict__ p1,
                                              const float* __restrict__ b1,
                                              const float* __restrict__ gamma,
                                              const float* __restrict__ beta,
                                              float* __restrict__ hn) {
    const int b = blockIdx.x;
    const int t = threadIdx.x;
    const int wave = t >> 6, lane = t & 63;
    __shared__ float red[4];

    float g[8];
    float ls = 0.f;
    #pragma unroll
    for (int i = 0; i < 8; ++i) {
        const int j = t + i * 256;
        float s = b1[j];
        #pragma unroll 8
        for (int ks = 0; ks < NSEG1; ++ks)
            s += p1[((size_t)ks * BATCH + b) * DIM2 + j];
        const float ge = 0.5f * s * (1.f + erff(s * 0.70710678118654752f));
        g[i] = ge;
        ls += ge;
    }

    float w = wave_sum(ls);
    if (lane == 0) red[wave] = w;
    __syncthreads();
    const float mu = (red[0] + red[1] + red[2] + red[3]) * (1.f / (float)DIM2);
    __syncthreads();

    float lv = 0.f;
    #pragma unroll
    for (int i = 0; i < 8; ++i) { const float d = g[i] - mu; lv += d * d; }
    w = wave_sum(lv);
    if (lane == 0) red[wave] = w;
    __syncthreads();
    const float var = (red[0] + red[1] + red[2] + red[3]) * (1.f / (float)DIM2);
    const float rs = rsqrtf(var + EPSF);

    #pragma unroll
    for (int i = 0; i < 8; ++i) {
        const int j = t + i * 256;
        hn[(size_t)b * DIM2 + j] = (g[i] - mu) * rs * gamma[j] + beta[j];
    }
}

// ---------------------------------------------------------------------------
// K3c: p2[ks][b][j] = partial dot over k-segment of hn[b,:] @ W2[:,j].
// ---------------------------------------------------------------------------
__global__ __launch_bounds__(256) void k3c_o(const float* __restrict__ hn,
                                             const float* __restrict__ W2,
                                             float* __restrict__ p2) {
    const int j  = blockIdx.x * 256 + threadIdx.x;  // 0..1023
    const int ks = blockIdx.y;
    const int k0 = ks * KSEG2;

    __shared__ float hl[BATCH][KSEG2];              // 4 KB
    for (int i = threadIdx.x; i < BATCH * KSEG2; i += 256)
        hl[i >> 5][i & 31] = hn[(size_t)(i >> 5) * DIM2 + k0 + (i & 31)];
    __syncthreads();

    float acc[BATCH];
    #pragma unroll
    for (int b = 0; b < BATCH; ++b) acc[b] = 0.f;

    #pragma unroll
    for (int k4 = 0; k4 < KSEG2 / 4; ++k4) {
        const float w0 = W2[(size_t)(k0 + 4 * k4 + 0) * DIM + j];
        const float w1 = W2[(size_t)(k0 + 4 * k4 + 1) * DIM + j];
        const float w2 = W2[(size_t)(k0 + 4 * k4 + 2) * DIM + j];
        const float w3 = W2[(size_t)(k0 + 4 * k4 + 3) * DIM + j];
        #pragma unroll
        for (int b = 0; b < BATCH; ++b) {
            const float4 h4 = *(const float4*)&hl[b][k4 * 4];
            acc[b] += h4.x * w0; acc[b] += h4.y * w1;
            acc[b] += h4.z * w2; acc[b] += h4.w * w3;
        }
    }
    #pragma unroll
    for (int b = 0; b < BATCH; ++b)
        p2[((size_t)ks * BATCH + b) * DIM + j] = acc[b];
}

// ---------------------------------------------------------------------------
// K4 (fused k3d): 8 blocks per batch. Each block computes pred[b] for its
// 4 cols/thread in registers (64 L2-hot float4 loads, address-independent),
// then streams its contiguous row range with nontemporal stores.
// ---------------------------------------------------------------------------
__global__ __launch_bounds__(256) void k4_scatter(const float* __restrict__ p2,
                                                  const float* __restrict__ b2,
                                                  const int* __restrict__ ntgt,
                                                  f4v* __restrict__ out,
                                                  int T) {
    const int g  = blockIdx.x;                // 0..7
    const int b  = blockIdx.y;
    const int d4 = threadIdx.x;               // 0..255 -> cols d4*4..+4
    const int n  = ntgt[b];

    float4 s = *(const float4*)(b2 + d4 * 4);
    #pragma unroll 8
    for (int ks = 0; ks < NSEG2; ++ks) {
        const float4 vv = *(const float4*)(p2 + ((size_t)ks * BATCH + b) * DIM + d4 * 4);
        s.x += vv.x; s.y += vv.y; s.z += vv.z; s.w += vv.w;
    }
    f4v p; p.x = s.x; p.y = s.y; p.z = s.z; p.w = s.w;
    const f4v z = (f4v)(0.f);

    const int R  = (T + K4_BLKS - 1) / K4_BLKS;   // rows per block
    const int t0 = g * R;
    f4v* o = out + ((size_t)b * T + t0) * 256 + d4;
    for (int r = 0; r < R; ++r) {
        const int tt = t0 + r;
        if (tt >= T) break;                   // block-uniform
        __builtin_nontemporal_store((tt < n) ? p : z, &o[(size_t)r * 256]);
    }
}

// ---------------------------------------------------------------------------
extern "C" void kernel_launch(void* const* d_in, const int* in_sizes, int n_in,
                              void* d_out, int out_size, void* d_ws, size_t ws_size,
                              hipStream_t stream) {
    const float* x     = (const float*)d_in[0];
    const int*   mask  = (const int*)d_in[1];   // int32 or int64 storage — sniffed in k1
    const float* W1    = (const float*)d_in[2];
    const float* b1    = (const float*)d_in[3];
    const float* gamma = (const float*)d_in[4];
    const float* beta  = (const float*)d_in[5];
    const float* W2    = (const float*)d_in[6];
    const float* b2    = (const float*)d_in[7];

    char* ws = (char*)d_ws;
    float* psum = (float*)(ws);                                   // 8 MB (aliased: p2 after k3a)
    float* p2   = psum;                                           // alias — psum dead after k3a
    float* p1   = (float*)(ws + (8u  << 20));                     // 8 MB
    float* hn   = (float*)(ws + (16u << 20));                     // 256 KB
    int*   cnt  = (int*)  (ws + (16u << 20) + (512u << 10));      // 128 B
    int*   ntgt = cnt + 64;                                       // 128 B

    const int T = out_size / (BATCH * DIM);   // num_targets, from output shape

    k1_fused <<<dim3(CHUNKS, BATCH), 256, 0, stream>>>(x, mask, psum, cnt, ntgt);
    k3a_h    <<<dim3(DIM2 / 256, NSEG1), 256, 0, stream>>>(psum, cnt, W1, p1);
    k3b_ln   <<<BATCH, 256, 0, stream>>>(p1, b1, gamma, beta, hn);
    k3c_o    <<<dim3(DIM / 256, NSEG2), 256, 0, stream>>>(hn, W2, p2);
    k4_scatter<<<dim3(K4_BLKS, BATCH), 256, 0, stream>>>(p2, b2, ntgt, (f4v*)d_out, T);
}

// Round 10
// 123.731 us; speedup vs baseline: 1.0080x; 1.0080x over previous
//
#include <hip/hip_runtime.h>
#include <math.h>

#define BATCH 32
#define LSEQ  2048
#define DIM   1024
#define DIM2  2048

constexpr float EPSF = 1e-5f;

constexpr int CHUNKS = 64;                    // max k1 chunks per batch (32 rows each)

constexpr int KSEG1 = 32;
constexpr int NSEG1 = DIM / KSEG1;            // 32 k-segments for matmul 1
constexpr int KSEG2 = 32;
constexpr int NSEG2 = DIM2 / KSEG2;           // 64 k-segments for matmul 2

constexpr int K4_BLKS = 8;                    // k4 blocks per batch

typedef float f4v __attribute__((ext_vector_type(4)));

// ---------------------------------------------------------------------------
// K0: per-batch compaction of context-row indices from target_mask (runs ONCE,
// 32 blocks — R9's per-k1-block recompute cost ~10 us, reverted).
// dtype sniff: mask storage may be int32 or int64; any nonzero at an odd
// int32 word => int32 (int64 high words all zero; P[false int64] = 2^-256).
// ---------------------------------------------------------------------------
__global__ __launch_bounds__(256) void k0_compact(const int* __restrict__ m32,
                                                  int* __restrict__ rowlist,
                                                  int* __restrict__ cnt,
                                                  int* __restrict__ ntgt) {
    const int b    = blockIdx.x;
    const int t    = threadIdx.x;
    const int wave = t >> 6, lane = t & 63;

    const int probe = m32[(size_t)b * 2048 + 8 * t + 1];
    __shared__ unsigned long long pbw[4];
    const unsigned long long pb = __ballot(probe != 0);
    if (lane == 0) pbw[wave] = pb;
    __syncthreads();
    const int stride = ((pbw[0] | pbw[1] | pbw[2] | pbw[3]) != 0ull) ? 1 : 2;

    const int base = t * 8;
    int f[8];
    int ls = 0;
    #pragma unroll
    for (int k = 0; k < 8; ++k) {
        f[k] = (m32[((size_t)b * 2048 + base + k) * (size_t)stride] == 0) ? 1 : 0;
        ls += f[k];
    }

    int v = ls;
    #pragma unroll
    for (int o = 1; o < 64; o <<= 1) {
        const int u = __shfl_up(v, o, 64);
        if (lane >= o) v += u;
    }
    __shared__ int wsum[4];
    if (lane == 63) wsum[wave] = v;
    __syncthreads();
    int wbase = 0;
    for (int w = 0; w < wave; ++w) wbase += wsum[w];
    const int excl = wbase + v - ls;          // exclusive offset for this thread

    int c = 0;
    #pragma unroll
    for (int k = 0; k < 8; ++k) {
        if (f[k]) { rowlist[(size_t)b * 2048 + excl + c] = base + k; ++c; }
    }
    if (t == 0) {
        const int tot = wsum[0] + wsum[1] + wsum[2] + wsum[3];
        cnt[b]  = tot;
        ntgt[b] = LSEQ - tot;
    }
}

// ---------------------------------------------------------------------------
// K1: gather-sum over context rows only (~50% of x never read) — R8 exact.
// ---------------------------------------------------------------------------
__global__ __launch_bounds__(256) void k1_gather(const float* __restrict__ x,
                                                 const int* __restrict__ rowlist,
                                                 const int* __restrict__ cnt,
                                                 float* __restrict__ psum) {
    const int chunk = blockIdx.x;
    const int b     = blockIdx.y;
    const int t     = threadIdx.x;            // 0..255 -> column group of 4

    const int cntb = cnt[b];
    const int nch  = (cntb + 31) >> 5;
    if (chunk >= nch) return;                 // block-uniform
    const int rbeg = chunk * 32;
    const int rcnt = min(32, cntb - rbeg);

    __shared__ int sidx[32];
    if (t < rcnt) sidx[t] = rowlist[(size_t)b * 2048 + rbeg + t];
    __syncthreads();

    const float* xb = x + (size_t)b * LSEQ * DIM + t * 4;
    float4 acc = make_float4(0.f, 0.f, 0.f, 0.f);

    if (rcnt == 32) {                         // fast path: unconditional
        #pragma unroll 8
        for (int r = 0; r < 32; ++r) {
            const float4 v = *(const float4*)(xb + (size_t)sidx[r] * DIM);
            acc.x += v.x; acc.y += v.y; acc.z += v.z; acc.w += v.w;
        }
    } else {                                  // one partial chunk per batch
        for (int r = 0; r < rcnt; ++r) {
            const float4 v = *(const float4*)(xb + (size_t)sidx[r] * DIM);
            acc.x += v.x; acc.y += v.y; acc.z += v.z; acc.w += v.w;
        }
    }

    *(float4*)(psum + ((size_t)b * CHUNKS + chunk) * DIM + t * 4) = acc;
}

// ---------------------------------------------------------------------------
// K3a (fused k2, R9 exact): stage mean directly from psum chunks (divide by
// cnt), then p1[ks][b][j] = mean[b, k-seg] @ W1[k-seg, j]. W1 read once.
// ---------------------------------------------------------------------------
__global__ __launch_bounds__(256) void k3a_h(const float* __restrict__ psum,
                                             const int* __restrict__ cnt,
                                             const float* __restrict__ W1,
                                             float* __restrict__ p1) {
    const int j  = blockIdx.x * 256 + threadIdx.x;  // 0..2047
    const int ks = blockIdx.y;
    const int k0 = ks * KSEG1;

    __shared__ float mlds[BATCH][KSEG1];            // 4 KB
    {
        const int b  = threadIdx.x >> 3;            // 0..31
        const int kq = threadIdx.x & 7;             // 0..7 -> cols kq*4..+4
        const int cb = cnt[b];
        const int nch = (cb + 31) >> 5;
        float4 s = make_float4(0.f, 0.f, 0.f, 0.f);
        for (int c = 0; c < nch; ++c) {
            const float4 vv = *(const float4*)(psum + ((size_t)b * CHUNKS + c) * DIM + k0 + kq * 4);
            s.x += vv.x; s.y += vv.y; s.z += vv.z; s.w += vv.w;
        }
        const float inv = 1.f / (float)(cb > 1 ? cb : 1);
        *(float4*)&mlds[b][kq * 4] = make_float4(s.x * inv, s.y * inv, s.z * inv, s.w * inv);
    }
    __syncthreads();

    float acc[BATCH];
    #pragma unroll
    for (int b = 0; b < BATCH; ++b) acc[b] = 0.f;

    #pragma unroll
    for (int k4 = 0; k4 < KSEG1 / 4; ++k4) {
        const float w0 = W1[(size_t)(k0 + 4 * k4 + 0) * DIM2 + j];
        const float w1 = W1[(size_t)(k0 + 4 * k4 + 1) * DIM2 + j];
        const float w2 = W1[(size_t)(k0 + 4 * k4 + 2) * DIM2 + j];
        const float w3 = W1[(size_t)(k0 + 4 * k4 + 3) * DIM2 + j];
        #pragma unroll
        for (int b = 0; b < BATCH; ++b) {
            const float4 m4 = *(const float4*)&mlds[b][k4 * 4];
            acc[b] += m4.x * w0; acc[b] += m4.y * w1;
            acc[b] += m4.z * w2; acc[b] += m4.w * w3;
        }
    }
    #pragma unroll
    for (int b = 0; b < BATCH; ++b)
        p1[((size_t)ks * BATCH + b) * DIM2 + j] = acc[b];
}

__device__ __forceinline__ float wave_sum(float v) {
    #pragma unroll
    for (int o = 32; o > 0; o >>= 1) v += __shfl_down(v, o, 64);
    return v;
}

// ---------------------------------------------------------------------------
// K3b: h = sum(p1) + b1; gelu(erf); LayerNorm -> hn. One block per batch row.
// ---------------------------------------------------------------------------
__global__ __launch_bounds__(256) void k3b_ln(const float* __restrict__ p1,
                                              const float* __restrict__ b1,
                                              const float* __restrict__ gamma,
                                              const float* __restrict__ beta,
                                              float* __restrict__ hn) {
    const int b = blockIdx.x;
    const int t = threadIdx.x;
    const int wave = t >> 6, lane = t & 63;
    __shared__ float red[4];

    float g[8];
    float ls = 0.f;
    #pragma unroll
    for (int i = 0; i < 8; ++i) {
        const int j = t + i * 256;
        float s = b1[j];
        #pragma unroll 8
        for (int ks = 0; ks < NSEG1; ++ks)
            s += p1[((size_t)ks * BATCH + b) * DIM2 + j];
        const float ge = 0.5f * s * (1.f + erff(s * 0.70710678118654752f));
        g[i] = ge;
        ls += ge;
    }

    float w = wave_sum(ls);
    if (lane == 0) red[wave] = w;
    __syncthreads();
    const float mu = (red[0] + red[1] + red[2] + red[3]) * (1.f / (float)DIM2);
    __syncthreads();

    float lv = 0.f;
    #pragma unroll
    for (int i = 0; i < 8; ++i) { const float d = g[i] - mu; lv += d * d; }
    w = wave_sum(lv);
    if (lane == 0) red[wave] = w;
    __syncthreads();
    const float var = (red[0] + red[1] + red[2] + red[3]) * (1.f / (float)DIM2);
    const float rs = rsqrtf(var + EPSF);

    #pragma unroll
    for (int i = 0; i < 8; ++i) {
        const int j = t + i * 256;
        hn[(size_t)b * DIM2 + j] = (g[i] - mu) * rs * gamma[j] + beta[j];
    }
}

// ---------------------------------------------------------------------------
// K3c: p2[ks][b][j] = partial dot over k-segment of hn[b,:] @ W2[:,j].
// ---------------------------------------------------------------------------
__global__ __launch_bounds__(256) void k3c_o(const float* __restrict__ hn,
                                             const float* __restrict__ W2,
                                             float* __restrict__ p2) {
    const int j  = blockIdx.x * 256 + threadIdx.x;  // 0..1023
    const int ks = blockIdx.y;
    const int k0 = ks * KSEG2;

    __shared__ float hl[BATCH][KSEG2];              // 4 KB
    for (int i = threadIdx.x; i < BATCH * KSEG2; i += 256)
        hl[i >> 5][i & 31] = hn[(size_t)(i >> 5) * DIM2 + k0 + (i & 31)];
    __syncthreads();

    float acc[BATCH];
    #pragma unroll
    for (int b = 0; b < BATCH; ++b) acc[b] = 0.f;

    #pragma unroll
    for (int k4 = 0; k4 < KSEG2 / 4; ++k4) {
        const float w0 = W2[(size_t)(k0 + 4 * k4 + 0) * DIM + j];
        const float w1 = W2[(size_t)(k0 + 4 * k4 + 1) * DIM + j];
        const float w2 = W2[(size_t)(k0 + 4 * k4 + 2) * DIM + j];
        const float w3 = W2[(size_t)(k0 + 4 * k4 + 3) * DIM + j];
        #pragma unroll
        for (int b = 0; b < BATCH; ++b) {
            const float4 h4 = *(const float4*)&hl[b][k4 * 4];
            acc[b] += h4.x * w0; acc[b] += h4.y * w1;
            acc[b] += h4.z * w2; acc[b] += h4.w * w3;
        }
    }
    #pragma unroll
    for (int b = 0; b < BATCH; ++b)
        p2[((size_t)ks * BATCH + b) * DIM + j] = acc[b];
}

// ---------------------------------------------------------------------------
// K4 (fused k3d, R9 exact): 8 blocks per batch; each computes pred[b] slice
// in registers from p2 (L2-hot), then streams contiguous rows, nt stores.
// ---------------------------------------------------------------------------
__global__ __launch_bounds__(256) void k4_scatter(const float* __restrict__ p2,
                                                  const float* __restrict__ b2,
                                                  const int* __restrict__ ntgt,
                                                  f4v* __restrict__ out,
                                                  int T) {
    const int g  = blockIdx.x;                // 0..7
    const int b  = blockIdx.y;
    const int d4 = threadIdx.x;               // 0..255 -> cols d4*4..+4
    const int n  = ntgt[b];

    float4 s = *(const float4*)(b2 + d4 * 4);
    #pragma unroll 8
    for (int ks = 0; ks < NSEG2; ++ks) {
        const float4 vv = *(const float4*)(p2 + ((size_t)ks * BATCH + b) * DIM + d4 * 4);
        s.x += vv.x; s.y += vv.y; s.z += vv.z; s.w += vv.w;
    }
    f4v p; p.x = s.x; p.y = s.y; p.z = s.z; p.w = s.w;
    const f4v z = (f4v)(0.f);

    const int R  = (T + K4_BLKS - 1) / K4_BLKS;   // rows per block
    const int t0 = g * R;
    f4v* o = out + ((size_t)b * T + t0) * 256 + d4;
    for (int r = 0; r < R; ++r) {
        const int tt = t0 + r;
        if (tt >= T) break;                   // block-uniform
        __builtin_nontemporal_store((tt < n) ? p : z, &o[(size_t)r * 256]);
    }
}

// ---------------------------------------------------------------------------
extern "C" void kernel_launch(void* const* d_in, const int* in_sizes, int n_in,
                              void* d_out, int out_size, void* d_ws, size_t ws_size,
                              hipStream_t stream) {
    const float* x     = (const float*)d_in[0];
    const int*   mask  = (const int*)d_in[1];   // int32 or int64 storage — sniffed in k0
    const float* W1    = (const float*)d_in[2];
    const float* b1    = (const float*)d_in[3];
    const float* gamma = (const float*)d_in[4];
    const float* beta  = (const float*)d_in[5];
    const float* W2    = (const float*)d_in[6];
    const float* b2    = (const float*)d_in[7];

    char* ws = (char*)d_ws;
    float* psum = (float*)(ws);                                   // 8 MB (aliased: p2 after k3a)
    float* p2   = psum;                                           // alias — psum dead after k3a
    float* p1   = (float*)(ws + (8u  << 20));                     // 8 MB
    float* hn   = (float*)(ws + (16u << 20));                     // 256 KB
    int* rowlist= (int*)  (ws + (17u << 20));                     // 256 KB
    int*   cnt  = rowlist + BATCH * LSEQ;                         // 128 B
    int*   ntgt = cnt + 64;                                       // 128 B

    const int T = out_size / (BATCH * DIM);   // num_targets, from output shape

    k0_compact<<<BATCH, 256, 0, stream>>>(mask, rowlist, cnt, ntgt);
    k1_gather<<<dim3(CHUNKS, BATCH), 256, 0, stream>>>(x, rowlist, cnt, psum);
    k3a_h    <<<dim3(DIM2 / 256, NSEG1), 256, 0, stream>>>(psum, cnt, W1, p1);
    k3b_ln   <<<BATCH, 256, 0, stream>>>(p1, b1, gamma, beta, hn);
    k3c_o    <<<dim3(DIM / 256, NSEG2), 256, 0, stream>>>(hn, W2, p2);
    k4_scatter<<<dim3(K4_BLKS, BATCH), 256, 0, stream>>>(p2, b2, ntgt, (f4v*)d_out, T);
}